// Round 10
// baseline (38750.781 us; speedup 1.0000x reference)
//
#include <hip/hip_runtime.h>

// ResLSTM: T=512, B=128, IN=H=1024, L=4.
// R10: weights-in-registers (R8's no-spill 352-reg/lane allocation, 256 thr,
// launch_bounds(256,1)) + R9's flag pipeline, with the coherence scheme fixed:
//  - A-panel loads are NORMAL CACHED (L2-shared within the XCD; R9's sc loads
//    pushed ~197 MB/t to L3 = the 63us/t wall),
//  - state stores are sc0/sc1 write-through (publish to coherence point),
//  - ONE agent-acquire fence per t per WG invalidates stale clean lines
//    (weights in regs = immune; c-carry lives in 8 f32 REGISTERS/lane),
//  - layer -> XCD-pair pinning: each XCD streams only its own layer's panels.

#define TT 512
#define BB 128
#define IN_D 1024
#define HH 1024
#define LL 4
#define G3 3072
#define SLOT (BB * HH)        // 131072
#define SLOT_ALL (LL * SLOT)  // 524288
#define NSL 4                 // state time-slots
#define NFS 8                 // flag time-slots

typedef __attribute__((ext_vector_type(8))) __bf16 bf16x8;
typedef __attribute__((ext_vector_type(4))) float f32x4;

__device__ __forceinline__ f32x4 mfma16(bf16x8 a, bf16x8 b, f32x4 c) {
    return __builtin_amdgcn_mfma_f32_16x16x32_bf16(a, b, c, 0, 0, 0);
}
__device__ __forceinline__ bf16x8 ldb(const __bf16* p, int k) {
    return *reinterpret_cast<const bf16x8*>(p + k);
}
__device__ __forceinline__ bf16x8 cvt8(float4 u, float4 v) {
    bf16x8 r;
    r[0] = (__bf16)u.x; r[1] = (__bf16)u.y; r[2] = (__bf16)u.z; r[3] = (__bf16)u.w;
    r[4] = (__bf16)v.x; r[5] = (__bf16)v.y; r[6] = (__bf16)v.z; r[7] = (__bf16)v.w;
    return r;
}
__device__ __forceinline__ bf16x8 cvt8p(const float* p) {
    float4 u = *reinterpret_cast<const float4*>(p);
    float4 v = *reinterpret_cast<const float4*>(p + 4);
    return cvt8(u, v);
}
__device__ __forceinline__ float sigm(float v) { return 1.f / (1.f + __expf(-v)); }
__device__ __forceinline__ float tanh_fast(float v) { return 1.f - 2.f / (1.f + __expf(2.f * v)); }
__device__ __forceinline__ unsigned bf16bits(float f) {
    __bf16 h = (__bf16)f;
    return (unsigned)__builtin_bit_cast(unsigned short, h);
}
__device__ __forceinline__ void st_b16_sc(__bf16* p, unsigned v) {
    asm volatile("global_store_short %0, %1, off sc0 sc1" :: "v"(p), "v"(v) : "memory");
}
#define LGKW { asm volatile("s_waitcnt lgkmcnt(0)" ::: "memory"); \
               __builtin_amdgcn_sched_barrier(0); }

__device__ __forceinline__ void waitg(const int* p, int tgt) {
    const int* q = p + (threadIdx.x & 63);
    for (;;) {
        int v;
        asm volatile("global_load_dword %0, %1, off sc0 sc1\n\ts_waitcnt vmcnt(0)"
                     : "=v"(v) : "v"(q) : "memory");
        if (__all(v >= tgt)) return;
        __builtin_amdgcn_s_sleep(2);
    }
}

// hidden [2L,B,H] -> bf16 state slot 3 ("t = -1")
__global__ void k_init(const float* __restrict__ hidden,
                       __bf16* __restrict__ hb, __bf16* __restrict__ cb) {
    const unsigned stride = gridDim.x * blockDim.x;
    for (unsigned i = blockIdx.x * blockDim.x + threadIdx.x; i < SLOT_ALL; i += stride) {
        hb[3u * SLOT_ALL + i] = (__bf16)hidden[i];
        cb[3u * SLOT_ALL + i] = (__bf16)hidden[SLOT_ALL + i];
    }
}

__global__ __launch_bounds__(256, 1) void k_persist(
    const float* __restrict__ x,
    const float* __restrict__ hidden,
    const float* __restrict__ Wii,
    const float* __restrict__ Wic,
    const float* __restrict__ Wih,
    const float* __restrict__ bii,
    const float* __restrict__ bic,
    const float* __restrict__ bih,
    const float* __restrict__ Whh,
    const float* __restrict__ bhh,
    const float* __restrict__ Wir,
    __bf16* __restrict__ hb,
    __bf16* __restrict__ cb,
    float* __restrict__ dout,
    int* __restrict__ done)
{
    __shared__ __align__(16) f32x4 exch[2][4][5][64];   // 40 KiB

    const int wgid = blockIdx.x;
    const int xcd = wgid & 7;
    const int j = xcd >> 1;                       // layer pinned to an XCD pair
    const int nwg = ((wgid >> 3) << 1) | (xcd & 1);
    const int n0 = nwg * 16;
    const int tid = threadIdx.x;
    const int lane = tid & 63;
    const int w = tid >> 6;                       // wave 0..3
    const int lrow = lane & 15;
    const int kgrp = lane >> 4;
    const int col = n0 + lrow;
    const int ofs = 32 * w + 8 * kgrp;

    // ---- one-time weight fragment load (f32 -> bf16 in-register), 88 frags ----
    bf16x8 wI[24], wF[24], wO[24], wC[8], wR[8];
    {
        const float* pi = Wii + (size_t)j * G3 * IN_D;
        const float* ph = Wih + (size_t)j * G3 * HH;
        const float* pc = Wic + (size_t)j * G3 * HH;
        const float* pw = Whh + (size_t)j * HH * HH;
        const float* pr = Wir + (size_t)j * HH * IN_D;
        #pragma unroll
        for (int q = 0; q < 8; ++q) {
            const int ko = (4 * q + w) * 32 + kgrp * 8;
            wI[q]      = cvt8p(pi + (size_t)col * IN_D + ko);
            wI[8 + q]  = cvt8p(ph + (size_t)col * HH + ko);
            wI[16 + q] = cvt8p(pc + (size_t)col * HH + ko);
            wF[q]      = cvt8p(pi + (size_t)(col + 1024) * IN_D + ko);
            wF[8 + q]  = cvt8p(ph + (size_t)(col + 1024) * HH + ko);
            wF[16 + q] = cvt8p(pc + (size_t)(col + 1024) * HH + ko);
            wO[q]      = cvt8p(pi + (size_t)(col + 2048) * IN_D + ko);
            wO[8 + q]  = cvt8p(ph + (size_t)(col + 2048) * HH + ko);
            wO[16 + q] = cvt8p(pc + (size_t)(col + 2048) * HH + ko);
            wC[q] = cvt8p(pw + (size_t)col * HH + ko);
            wR[q] = cvt8p(pr + (size_t)col * IN_D + ko);
        }
    }
    const float b_i = bii[j * G3 + col] + bih[j * G3 + col] + bic[j * G3 + col];
    const float b_f = bii[j * G3 + 1024 + col] + bih[j * G3 + 1024 + col] + bic[j * G3 + 1024 + col];
    const float b_o = bii[j * G3 + 2048 + col] + bih[j * G3 + 2048 + col] + bic[j * G3 + 2048 + col];
    const float b_c = bhh[j * HH + col];

    // ---- WG-private f32 c-carry in registers (wave w owns rows 32w..32w+31) ----
    f32x4 cf0, cf1;
    #pragma unroll
    for (int r = 0; r < 4; ++r) {
        cf0[r] = hidden[(size_t)(LL + j) * SLOT + (size_t)(32 * w + 4 * kgrp + r) * HH + col];
        cf1[r] = hidden[(size_t)(LL + j) * SLOT + (size_t)(32 * w + 16 + 4 * kgrp + r) * HH + col];
    }

    for (int t = 0; t < TT; ++t) {
        if (w == 0) {
            if (j > 0)                  waitg(done + ((j - 1) * NFS + (t & 7)) * 64, t);
            if (t >= 1)                 waitg(done + (j * NFS + ((t - 1) & 7)) * 64, t - 1);
            if (j < LL - 1 && t >= NSL) waitg(done + ((j + 1) * NFS + ((t - NSL) & 7)) * 64, t - NSL);
            __builtin_amdgcn_fence(__ATOMIC_ACQUIRE, "agent");
        }
        __builtin_amdgcn_s_barrier();
        __builtin_amdgcn_sched_barrier(0);

        const int sl = t & 3, slp = (t + 3) & 3;
        const __bf16* hP = hb + (size_t)slp * SLOT_ALL + (size_t)j * SLOT;
        const __bf16* cP = cb + (size_t)slp * SLOT_ALL + (size_t)j * SLOT;
        const __bf16* outP = hb + (size_t)sl * SLOT_ALL + (size_t)(j - 1) * SLOT;  // j>0
        const float*  xP = x + (size_t)t * SLOT;                                    // j==0
        __bf16* hD = hb + (size_t)sl * SLOT_ALL + (size_t)j * SLOT;
        __bf16* cD = cb + (size_t)sl * SLOT_ALL + (size_t)j * SLOT;

        #pragma unroll
        for (int m = 0; m < 8; ++m) {
            const size_t rofs = (size_t)(16 * m + lrow) * HH + ofs;
            f32x4 vI = {0,0,0,0}, vF = {0,0,0,0}, vO = {0,0,0,0},
                  vC = {0,0,0,0}, vR = {0,0,0,0};

            bf16x8 aH[8], aC[8];
            #pragma unroll
            for (int q = 0; q < 8; ++q) aH[q] = ldb(hP + rofs, 128 * q);

            if (j > 0) {
                bf16x8 aO[8];
                #pragma unroll
                for (int q = 0; q < 8; ++q) aO[q] = ldb(outP + rofs, 128 * q);
                #pragma unroll
                for (int q = 0; q < 8; ++q) {
                    vI = mfma16(aO[q], wI[q], vI); vF = mfma16(aO[q], wF[q], vF);
                    vO = mfma16(aO[q], wO[q], vO); vR = mfma16(aO[q], wR[q], vR);
                }
            } else {
                #pragma unroll
                for (int q = 0; q < 8; ++q) {
                    bf16x8 a = cvt8p(xP + rofs + 128 * q);
                    vI = mfma16(a, wI[q], vI); vF = mfma16(a, wF[q], vF);
                    vO = mfma16(a, wO[q], vO); vR = mfma16(a, wR[q], vR);
                }
            }
            #pragma unroll
            for (int q = 0; q < 8; ++q) aC[q] = ldb(cP + rofs, 128 * q);
            #pragma unroll
            for (int q = 0; q < 8; ++q) {
                vI = mfma16(aH[q], wI[8 + q], vI); vF = mfma16(aH[q], wF[8 + q], vF);
                vO = mfma16(aH[q], wO[8 + q], vO); vC = mfma16(aH[q], wC[q], vC);
            }
            #pragma unroll
            for (int q = 0; q < 8; ++q) {
                vI = mfma16(aC[q], wI[16 + q], vI); vF = mfma16(aC[q], wF[16 + q], vF);
                vO = mfma16(aC[q], wO[16 + q], vO);
            }

            exch[m & 1][w][0][lane] = vI;
            exch[m & 1][w][1][lane] = vF;
            exch[m & 1][w][2][lane] = vO;
            exch[m & 1][w][3][lane] = vC;
            exch[m & 1][w][4][lane] = vR;
            LGKW
            __builtin_amdgcn_s_barrier();

            if (w == (m >> 1)) {
                f32x4 sI = {0,0,0,0}, sF = {0,0,0,0}, sO = {0,0,0,0},
                      sC = {0,0,0,0}, sR = {0,0,0,0};
                #pragma unroll
                for (int ww = 0; ww < 4; ++ww) {
                    sI += exch[m & 1][ww][0][lane];
                    sF += exch[m & 1][ww][1][lane];
                    sO += exch[m & 1][ww][2][lane];
                    sC += exch[m & 1][ww][3][lane];
                    sR += exch[m & 1][ww][4][lane];
                }
                #pragma unroll
                for (int r = 0; r < 4; ++r) {
                    const int row = 16 * m + 4 * kgrp + r;
                    const size_t o = (size_t)row * HH + col;
                    float iv = sI[r] + b_i;
                    float fv = sF[r] + b_f;
                    float ov = sO[r] + b_o;
                    float cg = tanh_fast(sC[r] + b_c);
                    float cold = (m & 1) ? cf1[r] : cf0[r];
                    float cy = sigm(fv) * cold + sigm(iv) * cg;
                    float hy = sigm(ov) * (tanh_fast(cy) + sR[r]);
                    if (m & 1) cf1[r] = cy; else cf0[r] = cy;
                    st_b16_sc(hD + o, bf16bits(hy));
                    st_b16_sc(cD + o, bf16bits(cy));
                    if (j == LL - 1) dout[(size_t)t * SLOT + o] = hy;
                    if (t == TT - 1) {
                        dout[(size_t)TT * SLOT + (size_t)j * SLOT + o] = hy;
                        dout[(size_t)TT * SLOT + SLOT_ALL + (size_t)j * SLOT + o] = cy;
                    }
                }
            }
        }

        asm volatile("s_waitcnt vmcnt(0)" ::: "memory");
        __builtin_amdgcn_s_barrier();
        if (tid == 0) {
            int* fp = done + (j * NFS + (t & 7)) * 64 + nwg;
            asm volatile("global_store_dword %0, %1, off sc0 sc1" :: "v"(fp), "v"(t) : "memory");
        }
    }
}

extern "C" void kernel_launch(void* const* d_in, const int* in_sizes, int n_in,
                              void* d_out, int out_size, void* d_ws, size_t ws_size,
                              hipStream_t stream) {
    const float* x      = (const float*)d_in[0];
    const float* hidden = (const float*)d_in[1];
    const float* Wii    = (const float*)d_in[2];
    const float* Wic    = (const float*)d_in[3];
    const float* Wih    = (const float*)d_in[4];
    const float* bii    = (const float*)d_in[5];
    const float* bic    = (const float*)d_in[6];
    const float* bih    = (const float*)d_in[7];
    const float* Whh    = (const float*)d_in[8];
    const float* bhh    = (const float*)d_in[9];
    const float* Wir    = (const float*)d_in[10];
    float* out = (float*)d_out;

    // ws layout (bytes): hb @0 4,194,304 | cb @4194304 4,194,304 | done @8388608 8,192
    char* ws = (char*)d_ws;
    __bf16* hb   = (__bf16*)(ws);
    __bf16* cb   = (__bf16*)(ws + 4194304);
    int*    done = (int*)(ws + 8388608);

    hipMemsetAsync(done, 0xFF, LL * NFS * 64 * sizeof(int), stream);
    k_init<<<1024, 256, 0, stream>>>(hidden, hb, cb);

    k_persist<<<dim3(256), dim3(256), 0, stream>>>(x, hidden, Wii, Wic, Wih,
                                                   bii, bic, bih, Whh, bhh, Wir,
                                                   hb, cb, out, done);
}

// Round 11
// 37875.781 us; speedup vs baseline: 1.0231x; 1.0231x over previous
//
#include <hip/hip_runtime.h>

// ResLSTM: T=512, B=128, IN=H=1024, L=4.
// R11: R10 (weights-in-registers, flag pipeline, register c-carry, cached panel
// loads) + 32-deep state RING with fences every 16 t instead of every t.
// Freshness by construction: slot addr written at t0 is only read in [t0,t0+4]
// and previously touched at t0-32..t0-28; fences every 16 t guarantee >=1
// invalidation in (t0-28,t0], so post-fence reads always miss and pull the
// sc0sc1-published line from the coherence point. L2-inv thrash /16, panels
// stay L2-shared, layer skew window widens to 32 (straggler elasticity).

#define TT 512
#define BB 128
#define IN_D 1024
#define HH 1024
#define LL 4
#define G3 3072
#define SLOT (BB * HH)        // 131072
#define SLOT_ALL (LL * SLOT)  // 524288
#define NSL 32                // state ring depth
#define FENCE_P 16            // fence period (t)
#define NFS 8                 // flag time-slots (value-compared, lap-safe)

typedef __attribute__((ext_vector_type(8))) __bf16 bf16x8;
typedef __attribute__((ext_vector_type(4))) float f32x4;

__device__ __forceinline__ f32x4 mfma16(bf16x8 a, bf16x8 b, f32x4 c) {
    return __builtin_amdgcn_mfma_f32_16x16x32_bf16(a, b, c, 0, 0, 0);
}
__device__ __forceinline__ bf16x8 ldb(const __bf16* p, int k) {
    return *reinterpret_cast<const bf16x8*>(p + k);
}
__device__ __forceinline__ bf16x8 cvt8(float4 u, float4 v) {
    bf16x8 r;
    r[0] = (__bf16)u.x; r[1] = (__bf16)u.y; r[2] = (__bf16)u.z; r[3] = (__bf16)u.w;
    r[4] = (__bf16)v.x; r[5] = (__bf16)v.y; r[6] = (__bf16)v.z; r[7] = (__bf16)v.w;
    return r;
}
__device__ __forceinline__ bf16x8 cvt8p(const float* p) {
    float4 u = *reinterpret_cast<const float4*>(p);
    float4 v = *reinterpret_cast<const float4*>(p + 4);
    return cvt8(u, v);
}
__device__ __forceinline__ float sigm(float v) { return 1.f / (1.f + __expf(-v)); }
__device__ __forceinline__ float tanh_fast(float v) { return 1.f - 2.f / (1.f + __expf(2.f * v)); }
__device__ __forceinline__ unsigned bf16bits(float f) {
    __bf16 h = (__bf16)f;
    return (unsigned)__builtin_bit_cast(unsigned short, h);
}
__device__ __forceinline__ void st_b16_sc(__bf16* p, unsigned v) {
    asm volatile("global_store_short %0, %1, off sc0 sc1" :: "v"(p), "v"(v) : "memory");
}
#define LGKW { asm volatile("s_waitcnt lgkmcnt(0)" ::: "memory"); \
               __builtin_amdgcn_sched_barrier(0); }

__device__ __forceinline__ void waitg(const int* p, int tgt) {
    const int* q = p + (threadIdx.x & 63);
    for (;;) {
        int v;
        asm volatile("global_load_dword %0, %1, off sc0 sc1\n\ts_waitcnt vmcnt(0)"
                     : "=v"(v) : "v"(q) : "memory");
        if (__all(v >= tgt)) return;
        __builtin_amdgcn_s_sleep(1);
    }
}

// hidden [2L,B,H] -> bf16 state ring slot 31 ("t = -1")
__global__ void k_init(const float* __restrict__ hidden,
                       __bf16* __restrict__ hb, __bf16* __restrict__ cb) {
    const unsigned stride = gridDim.x * blockDim.x;
    for (unsigned i = blockIdx.x * blockDim.x + threadIdx.x; i < SLOT_ALL; i += stride) {
        hb[31u * SLOT_ALL + i] = (__bf16)hidden[i];
        cb[31u * SLOT_ALL + i] = (__bf16)hidden[SLOT_ALL + i];
    }
}

__global__ __launch_bounds__(256, 1) void k_persist(
    const float* __restrict__ x,
    const float* __restrict__ hidden,
    const float* __restrict__ Wii,
    const float* __restrict__ Wic,
    const float* __restrict__ Wih,
    const float* __restrict__ bii,
    const float* __restrict__ bic,
    const float* __restrict__ bih,
    const float* __restrict__ Whh,
    const float* __restrict__ bhh,
    const float* __restrict__ Wir,
    __bf16* __restrict__ hb,
    __bf16* __restrict__ cb,
    float* __restrict__ dout,
    int* __restrict__ done)
{
    __shared__ __align__(16) f32x4 exch[2][4][5][64];   // 40 KiB

    const int wgid = blockIdx.x;
    const int xcd = wgid & 7;
    const int j = xcd >> 1;                       // layer pinned to an XCD pair
    const int nwg = ((wgid >> 3) << 1) | (xcd & 1);
    const int n0 = nwg * 16;
    const int tid = threadIdx.x;
    const int lane = tid & 63;
    const int w = tid >> 6;                       // wave 0..3
    const int lrow = lane & 15;
    const int kgrp = lane >> 4;
    const int col = n0 + lrow;
    const int ofs = 32 * w + 8 * kgrp;

    // ---- one-time weight fragment load (f32 -> bf16 in-register), 88 frags ----
    bf16x8 wI[24], wF[24], wO[24], wC[8], wR[8];
    {
        const float* pi = Wii + (size_t)j * G3 * IN_D;
        const float* ph = Wih + (size_t)j * G3 * HH;
        const float* pc = Wic + (size_t)j * G3 * HH;
        const float* pw = Whh + (size_t)j * HH * HH;
        const float* pr = Wir + (size_t)j * HH * IN_D;
        #pragma unroll
        for (int q = 0; q < 8; ++q) {
            const int ko = (4 * q + w) * 32 + kgrp * 8;
            wI[q]      = cvt8p(pi + (size_t)col * IN_D + ko);
            wI[8 + q]  = cvt8p(ph + (size_t)col * HH + ko);
            wI[16 + q] = cvt8p(pc + (size_t)col * HH + ko);
            wF[q]      = cvt8p(pi + (size_t)(col + 1024) * IN_D + ko);
            wF[8 + q]  = cvt8p(ph + (size_t)(col + 1024) * HH + ko);
            wF[16 + q] = cvt8p(pc + (size_t)(col + 1024) * HH + ko);
            wO[q]      = cvt8p(pi + (size_t)(col + 2048) * IN_D + ko);
            wO[8 + q]  = cvt8p(ph + (size_t)(col + 2048) * HH + ko);
            wO[16 + q] = cvt8p(pc + (size_t)(col + 2048) * HH + ko);
            wC[q] = cvt8p(pw + (size_t)col * HH + ko);
            wR[q] = cvt8p(pr + (size_t)col * IN_D + ko);
        }
    }
    const float b_i = bii[j * G3 + col] + bih[j * G3 + col] + bic[j * G3 + col];
    const float b_f = bii[j * G3 + 1024 + col] + bih[j * G3 + 1024 + col] + bic[j * G3 + 1024 + col];
    const float b_o = bii[j * G3 + 2048 + col] + bih[j * G3 + 2048 + col] + bic[j * G3 + 2048 + col];
    const float b_c = bhh[j * HH + col];

    // ---- WG-private f32 c-carry in registers (wave w owns rows 32w..32w+31) ----
    f32x4 cf0, cf1;
    #pragma unroll
    for (int r = 0; r < 4; ++r) {
        cf0[r] = hidden[(size_t)(LL + j) * SLOT + (size_t)(32 * w + 4 * kgrp + r) * HH + col];
        cf1[r] = hidden[(size_t)(LL + j) * SLOT + (size_t)(32 * w + 16 + 4 * kgrp + r) * HH + col];
    }

    for (int t = 0; t < TT; ++t) {
        // ---- dependency waits (wave 0); fence only every FENCE_P steps ----
        if (w == 0) {
            if (j > 0)                  waitg(done + ((j - 1) * NFS + (t & 7)) * 64, t);
            if (t >= 1)                 waitg(done + (j * NFS + ((t - 1) & 7)) * 64, t - 1);
            if (j < LL - 1 && t >= NSL) waitg(done + ((j + 1) * NFS + ((t - NSL) & 7)) * 64, t - NSL);
            if ((t & (FENCE_P - 1)) == 0)
                __builtin_amdgcn_fence(__ATOMIC_ACQUIRE, "agent");
        }
        __builtin_amdgcn_s_barrier();
        __builtin_amdgcn_sched_barrier(0);

        const int sl = t & 31, slp = (t + 31) & 31;
        const __bf16* hP = hb + (size_t)slp * SLOT_ALL + (size_t)j * SLOT;
        const __bf16* cP = cb + (size_t)slp * SLOT_ALL + (size_t)j * SLOT;
        const __bf16* outP = hb + (size_t)sl * SLOT_ALL + (size_t)(j - 1) * SLOT;  // j>0
        const float*  xP = x + (size_t)t * SLOT;                                    // j==0
        __bf16* hD = hb + (size_t)sl * SLOT_ALL + (size_t)j * SLOT;
        __bf16* cD = cb + (size_t)sl * SLOT_ALL + (size_t)j * SLOT;

        #pragma unroll
        for (int m = 0; m < 8; ++m) {
            const size_t rofs = (size_t)(16 * m + lrow) * HH + ofs;
            f32x4 vI = {0,0,0,0}, vF = {0,0,0,0}, vO = {0,0,0,0},
                  vC = {0,0,0,0}, vR = {0,0,0,0};

            bf16x8 aH[8], aC[8];
            #pragma unroll
            for (int q = 0; q < 8; ++q) aH[q] = ldb(hP + rofs, 128 * q);

            if (j > 0) {
                bf16x8 aO[8];
                #pragma unroll
                for (int q = 0; q < 8; ++q) aO[q] = ldb(outP + rofs, 128 * q);
                #pragma unroll
                for (int q = 0; q < 8; ++q) {
                    vI = mfma16(aO[q], wI[q], vI); vF = mfma16(aO[q], wF[q], vF);
                    vO = mfma16(aO[q], wO[q], vO); vR = mfma16(aO[q], wR[q], vR);
                }
            } else {
                #pragma unroll
                for (int q = 0; q < 8; ++q) {
                    bf16x8 a = cvt8p(xP + rofs + 128 * q);
                    vI = mfma16(a, wI[q], vI); vF = mfma16(a, wF[q], vF);
                    vO = mfma16(a, wO[q], vO); vR = mfma16(a, wR[q], vR);
                }
            }
            #pragma unroll
            for (int q = 0; q < 8; ++q) aC[q] = ldb(cP + rofs, 128 * q);
            #pragma unroll
            for (int q = 0; q < 8; ++q) {
                vI = mfma16(aH[q], wI[8 + q], vI); vF = mfma16(aH[q], wF[8 + q], vF);
                vO = mfma16(aH[q], wO[8 + q], vO); vC = mfma16(aH[q], wC[q], vC);
            }
            #pragma unroll
            for (int q = 0; q < 8; ++q) {
                vI = mfma16(aC[q], wI[16 + q], vI); vF = mfma16(aC[q], wF[16 + q], vF);
                vO = mfma16(aC[q], wO[16 + q], vO);
            }

            exch[m & 1][w][0][lane] = vI;
            exch[m & 1][w][1][lane] = vF;
            exch[m & 1][w][2][lane] = vO;
            exch[m & 1][w][3][lane] = vC;
            exch[m & 1][w][4][lane] = vR;
            LGKW
            __builtin_amdgcn_s_barrier();

            if (w == (m >> 1)) {
                f32x4 sI = {0,0,0,0}, sF = {0,0,0,0}, sO = {0,0,0,0},
                      sC = {0,0,0,0}, sR = {0,0,0,0};
                #pragma unroll
                for (int ww = 0; ww < 4; ++ww) {
                    sI += exch[m & 1][ww][0][lane];
                    sF += exch[m & 1][ww][1][lane];
                    sO += exch[m & 1][ww][2][lane];
                    sC += exch[m & 1][ww][3][lane];
                    sR += exch[m & 1][ww][4][lane];
                }
                #pragma unroll
                for (int r = 0; r < 4; ++r) {
                    const int row = 16 * m + 4 * kgrp + r;
                    const size_t o = (size_t)row * HH + col;
                    float iv = sI[r] + b_i;
                    float fv = sF[r] + b_f;
                    float ov = sO[r] + b_o;
                    float cg = tanh_fast(sC[r] + b_c);
                    float cold = (m & 1) ? cf1[r] : cf0[r];
                    float cy = sigm(fv) * cold + sigm(iv) * cg;
                    float hy = sigm(ov) * (tanh_fast(cy) + sR[r]);
                    if (m & 1) cf1[r] = cy; else cf0[r] = cy;
                    st_b16_sc(hD + o, bf16bits(hy));
                    st_b16_sc(cD + o, bf16bits(cy));
                    if (j == LL - 1) dout[(size_t)t * SLOT + o] = hy;
                    if (t == TT - 1) {
                        dout[(size_t)TT * SLOT + (size_t)j * SLOT + o] = hy;
                        dout[(size_t)TT * SLOT + SLOT_ALL + (size_t)j * SLOT + o] = cy;
                    }
                }
            }
        }

        // ---- all sc stores retired -> single-writer flag ----
        asm volatile("s_waitcnt vmcnt(0)" ::: "memory");
        __builtin_amdgcn_s_barrier();
        if (tid == 0) {
            int* fp = done + (j * NFS + (t & 7)) * 64 + nwg;
            asm volatile("global_store_dword %0, %1, off sc0 sc1" :: "v"(fp), "v"(t) : "memory");
        }
    }
}

extern "C" void kernel_launch(void* const* d_in, const int* in_sizes, int n_in,
                              void* d_out, int out_size, void* d_ws, size_t ws_size,
                              hipStream_t stream) {
    const float* x      = (const float*)d_in[0];
    const float* hidden = (const float*)d_in[1];
    const float* Wii    = (const float*)d_in[2];
    const float* Wic    = (const float*)d_in[3];
    const float* Wih    = (const float*)d_in[4];
    const float* bii    = (const float*)d_in[5];
    const float* bic    = (const float*)d_in[6];
    const float* bih    = (const float*)d_in[7];
    const float* Whh    = (const float*)d_in[8];
    const float* bhh    = (const float*)d_in[9];
    const float* Wir    = (const float*)d_in[10];
    float* out = (float*)d_out;

    // ws layout (bytes):
    //   hb   @ 0          33,554,432   (32-slot ring, bf16)
    //   cb   @ 33554432   33,554,432
    //   done @ 67108864        8,192
    char* ws = (char*)d_ws;
    __bf16* hb   = (__bf16*)(ws);
    __bf16* cb   = (__bf16*)(ws + 33554432);
    int*    done = (int*)(ws + 67108864);

    hipMemsetAsync(done, 0xFF, LL * NFS * 64 * sizeof(int), stream);
    k_init<<<1024, 256, 0, stream>>>(hidden, hb, cb);

    k_persist<<<dim3(256), dim3(256), 0, stream>>>(x, hidden, Wii, Wic, Wih,
                                                   bii, bic, bih, Whh, bhh, Wir,
                                                   hb, cb, out, done);
}